// Round 1
// baseline (3500.045 us; speedup 1.0000x reference)
//
#include <hip/hip_runtime.h>
#include <hip/hip_bf16.h>

// Problem constants (MultiStepDecoder)
#define NB     32
#define NN     128
#define NE     16256
#define ND     64
#define NHID   128
#define NM     128
#define NOH    256
#define NT     2
#define EHALF  8128          // NE/2
#define NCHUNK 8             // chunks per half
#define CHUNK_E 1016         // EHALF / NCHUNK (exact)
#define TILE   32            // edges per inner tile
#define NTILES 32            // ceil(CHUNK_E / TILE) -> last tile has 24

__device__ __forceinline__ float4 ldg4(const float* p) {
    return *reinterpret_cast<const float4*>(p);
}

// ---------------------------------------------------------------------------
// K1: fused pre_msg + edge MLP (both rel types) + partial aggregation.
// grid = NB * 16  (16 = 2 halves * 8 chunks). block = 256.
// Each wg owns 1016 edges of one (b, half); accumulates its 128x128 partial
// of agg[b] in registers (8x8 per thread) and writes it to ws.
// ---------------------------------------------------------------------------
__global__ __launch_bounds__(256)
void k_edge(const float* __restrict__ inputs,
            const float* __restrict__ rel_rec,
            const float* __restrict__ rel_send,
            const float* __restrict__ rel_type,
            const int*   __restrict__ indices,
            const float* __restrict__ w1, const float* __restrict__ b1,
            const float* __restrict__ w2, const float* __restrict__ b2,
            const float* __restrict__ w3, const float* __restrict__ b3,
            const float* __restrict__ w4, const float* __restrict__ b4,
            float* __restrict__ partial)
{
    const int t     = threadIdx.x;
    const int wg    = blockIdx.x;        // 0..511
    const int b     = wg >> 4;
    const int c     = wg & 15;
    const int half  = c >> 3;
    const int chunk = c & 7;

    const float* WA = half ? w3 : w1;    // (T, NHID, ND)
    const float* BA = half ? b3 : b1;    // (T, NHID)
    const float* WB = half ? w4 : w2;    // (T, NM, NHID)
    const float* BB = half ? b4 : b2;    // (T, NM)

    __shared__ float inp_s[NN * ND];     // 32 KB  inputs[b], persistent
    __shared__ float rsrr [TILE * NN];   // 16 KB  rel_send rows, then rel_rec rows
    __shared__ float x_s  [TILE * ND];   //  8 KB  pre_msg tile
    __shared__ float h1_s [TILE * NHID]; // 16 KB  hidden tile
    __shared__ float msg_s[TILE * NM];   // 16 KB  message tile (sum over i)
    __shared__ float rt_s [TILE * NT];
    __shared__ int   eg_s [TILE];

    // stage inputs[b] (8192 floats)
    {
        const float4* src = reinterpret_cast<const float4*>(inputs + (size_t)b * NN * ND);
        float4* dst = reinterpret_cast<float4*>(inp_s);
        for (int i = t; i < NN * ND / 4; i += 256) dst[i] = src[i];
    }

    float agg[8][8];
#pragma unroll
    for (int k = 0; k < 8; ++k)
#pragma unroll
        for (int q = 0; q < 8; ++q) agg[k][q] = 0.f;

    const int tn = t >> 4;      // n-block 0..15 (agg rows tn*8..+7)
    const int tm = t & 15;      // m-block 0..15 (agg cols tm*8..+7)
    const int q0 = (t & 31) * 4; // h/m quad for MLP phases
    const int e0 = (t >> 5) * 4; // e quad for MLP phases
    const int jbase = chunk * CHUNK_E;

    for (int tt = 0; tt < NTILES; ++tt) {
        const int j0  = jbase + tt * TILE;
        const int cnt = min(TILE, jbase + CHUNK_E - j0);   // 32, last tile 24

        __syncthreads();   // previous tile's rsrr/msg_s fully consumed
        if (t < TILE) {
            int e = 0;
            if (t < cnt) {
                e = indices[half * EHALF + j0 + t];
                rt_s[t * 2 + 0] = rel_type[((size_t)b * NE + e) * NT + 0];
                rt_s[t * 2 + 1] = rel_type[((size_t)b * NE + e) * NT + 1];
            }
            eg_s[t] = e;
        }
        __syncthreads();

        // P1: load rel_send rows of this tile (coalesced float4)
        for (int i = t; i < cnt * (NN / 4); i += 256) {
            const int e  = i >> 5;          // NN/4 == 32
            const int nq = i & 31;
            reinterpret_cast<float4*>(rsrr)[e * 32 + nq] =
                reinterpret_cast<const float4*>(rel_send)[(size_t)eg_s[e] * 32 + nq];
        }
        __syncthreads();

        // P2: x[e][d] = sum_n rs[e][n] * inp[n][d]   (thread: e = t>>3, d-octet)
        {
            const int e  = t >> 3;
            const int d0 = (t & 7) * 8;
            if (e < cnt) {
                float acc[8];
#pragma unroll
                for (int k = 0; k < 8; ++k) acc[k] = 0.f;
#pragma unroll 4
                for (int n = 0; n < NN; ++n) {
                    const float r = rsrr[e * NN + n];
                    const float* ip = &inp_s[n * ND + d0];
#pragma unroll
                    for (int k = 0; k < 8; ++k) acc[k] += r * ip[k];
                }
#pragma unroll
                for (int k = 0; k < 8; ++k) x_s[e * ND + d0 + k] = acc[k];
            }
        }
        __syncthreads();

        // P3: prefetch rel_rec rows into rsrr (consumed in P5; barriers below order it)
        for (int i = t; i < cnt * (NN / 4); i += 256) {
            const int e  = i >> 5;
            const int nq = i & 31;
            reinterpret_cast<float4*>(rsrr)[e * 32 + nq] =
                reinterpret_cast<const float4*>(rel_rec)[(size_t)eg_s[e] * 32 + nq];
        }

        // P4: message MLP; msg accumulated over i in registers
        float accm[4][4];
#pragma unroll
        for (int er = 0; er < 4; ++er)
#pragma unroll
            for (int mj = 0; mj < 4; ++mj) accm[er][mj] = 0.f;

        for (int i = 0; i < NT; ++i) {
            // P4a: h1 = relu(x @ WA[i]^T + BA[i])   (4 h x 4 e per thread)
            {
                float acc[4][4];
#pragma unroll
                for (int er = 0; er < 4; ++er)
#pragma unroll
                    for (int hj = 0; hj < 4; ++hj) acc[er][hj] = 0.f;
                const float* wb = WA + ((size_t)i * NHID + q0) * ND;
#pragma unroll 2
                for (int dq = 0; dq < ND / 4; ++dq) {
                    const float4 wv0 = ldg4(wb + 0 * ND + dq * 4);
                    const float4 wv1 = ldg4(wb + 1 * ND + dq * 4);
                    const float4 wv2 = ldg4(wb + 2 * ND + dq * 4);
                    const float4 wv3 = ldg4(wb + 3 * ND + dq * 4);
#pragma unroll
                    for (int er = 0; er < 4; ++er) {
                        const float4 xv = *reinterpret_cast<const float4*>(&x_s[(e0 + er) * ND + dq * 4]);
                        acc[er][0] += xv.x * wv0.x + xv.y * wv0.y + xv.z * wv0.z + xv.w * wv0.w;
                        acc[er][1] += xv.x * wv1.x + xv.y * wv1.y + xv.z * wv1.z + xv.w * wv1.w;
                        acc[er][2] += xv.x * wv2.x + xv.y * wv2.y + xv.z * wv2.z + xv.w * wv2.w;
                        acc[er][3] += xv.x * wv3.x + xv.y * wv3.y + xv.z * wv3.z + xv.w * wv3.w;
                    }
                }
#pragma unroll
                for (int er = 0; er < 4; ++er) {
                    const int e = e0 + er;
                    if (e < cnt) {
                        float4 hv;
                        hv.x = fmaxf(acc[er][0] + BA[i * NHID + q0 + 0], 0.f);
                        hv.y = fmaxf(acc[er][1] + BA[i * NHID + q0 + 1], 0.f);
                        hv.z = fmaxf(acc[er][2] + BA[i * NHID + q0 + 2], 0.f);
                        hv.w = fmaxf(acc[er][3] + BA[i * NHID + q0 + 3], 0.f);
                        *reinterpret_cast<float4*>(&h1_s[e * NHID + q0]) = hv;
                    }
                }
            }
            __syncthreads();
            // P4b: m = relu(h1 @ WB[i]^T + BB[i]) * rt ; accumulate into accm
            {
                float acc[4][4];
#pragma unroll
                for (int er = 0; er < 4; ++er)
#pragma unroll
                    for (int mj = 0; mj < 4; ++mj) acc[er][mj] = 0.f;
                const float* wb = WB + ((size_t)i * NM + q0) * NHID;
#pragma unroll 2
                for (int hq = 0; hq < NHID / 4; ++hq) {
                    const float4 wv0 = ldg4(wb + 0 * NHID + hq * 4);
                    const float4 wv1 = ldg4(wb + 1 * NHID + hq * 4);
                    const float4 wv2 = ldg4(wb + 2 * NHID + hq * 4);
                    const float4 wv3 = ldg4(wb + 3 * NHID + hq * 4);
#pragma unroll
                    for (int er = 0; er < 4; ++er) {
                        const float4 hv = *reinterpret_cast<const float4*>(&h1_s[(e0 + er) * NHID + hq * 4]);
                        acc[er][0] += hv.x * wv0.x + hv.y * wv0.y + hv.z * wv0.z + hv.w * wv0.w;
                        acc[er][1] += hv.x * wv1.x + hv.y * wv1.y + hv.z * wv1.z + hv.w * wv1.w;
                        acc[er][2] += hv.x * wv2.x + hv.y * wv2.y + hv.z * wv2.z + hv.w * wv2.w;
                        acc[er][3] += hv.x * wv3.x + hv.y * wv3.y + hv.z * wv3.z + hv.w * wv3.w;
                    }
                }
#pragma unroll
                for (int er = 0; er < 4; ++er) {
                    const int e = e0 + er;
                    if (e < cnt) {
                        const float rt = rt_s[e * 2 + i];
                        accm[er][0] += fmaxf(acc[er][0] + BB[i * NM + q0 + 0], 0.f) * rt;
                        accm[er][1] += fmaxf(acc[er][1] + BB[i * NM + q0 + 1], 0.f) * rt;
                        accm[er][2] += fmaxf(acc[er][2] + BB[i * NM + q0 + 2], 0.f) * rt;
                        accm[er][3] += fmaxf(acc[er][3] + BB[i * NM + q0 + 3], 0.f) * rt;
                    }
                }
            }
            __syncthreads();   // h1_s reused next i / msg_s written next
        }

        // write msg tile
#pragma unroll
        for (int er = 0; er < 4; ++er) {
            const int e = e0 + er;
            if (e < cnt) {
                *reinterpret_cast<float4*>(&msg_s[e * NM + q0]) =
                    make_float4(accm[er][0], accm[er][1], accm[er][2], accm[er][3]);
            }
        }
        __syncthreads();   // msg_s ready; rel_rec prefetch (P3) also drained

        // P5: agg[n][m] += sum_e rr[e][n] * msg[e][m]
        {
            const float4* rr4 = reinterpret_cast<const float4*>(rsrr);
            const float4* mg4 = reinterpret_cast<const float4*>(msg_s);
            for (int e = 0; e < cnt; ++e) {
                const float4 a0 = rr4[e * 32 + tn * 2 + 0];
                const float4 a1 = rr4[e * 32 + tn * 2 + 1];
                const float4 m0 = mg4[e * 32 + tm * 2 + 0];
                const float4 m1 = mg4[e * 32 + tm * 2 + 1];
                const float ra[8] = {a0.x, a0.y, a0.z, a0.w, a1.x, a1.y, a1.z, a1.w};
                const float mv[8] = {m0.x, m0.y, m0.z, m0.w, m1.x, m1.y, m1.z, m1.w};
#pragma unroll
                for (int k = 0; k < 8; ++k)
#pragma unroll
                    for (int q = 0; q < 8; ++q)
                        agg[k][q] += ra[k] * mv[q];
            }
        }
    }

    // write 128x128 partial agg for this wg
    {
        float* dst = partial + (size_t)wg * (NN * NM);
#pragma unroll
        for (int k = 0; k < 8; ++k) {
            float* row = dst + (tn * 8 + k) * NM + tm * 8;
            *reinterpret_cast<float4*>(row)     = make_float4(agg[k][0], agg[k][1], agg[k][2], agg[k][3]);
            *reinterpret_cast<float4*>(row + 4) = make_float4(agg[k][4], agg[k][5], agg[k][6], agg[k][7]);
        }
    }
}

// ---------------------------------------------------------------------------
// K2: reduce 16 partials -> agg rows, then node MLP 128->256->256->64 + residual.
// grid = NB * 8 (16 rows each). block = 256.
// ---------------------------------------------------------------------------
__global__ __launch_bounds__(256)
void k_out(const float* __restrict__ partial,
           const float* __restrict__ inputs,
           const float* __restrict__ ow1, const float* __restrict__ ob1,
           const float* __restrict__ ow2, const float* __restrict__ ob2,
           const float* __restrict__ ow3, const float* __restrict__ ob3,
           float* __restrict__ out)
{
    const int t  = threadIdx.x;
    const int wg = blockIdx.x;      // 0..255
    const int b  = wg >> 3;
    const int n0 = (wg & 7) * 16;

    __shared__ float xr[16 * NM];    //  8 KB
    __shared__ float h1[16 * NOH];   // 16 KB
    __shared__ float h2[16 * NOH];   // 16 KB

    // reduce the 16 per-chunk partials for rows n0..n0+15
    for (int i = t; i < 16 * NM; i += 256) {
        const int r = i >> 7, m = i & 127;
        const float* p = partial + (size_t)(b * 16) * (NN * NM) + (size_t)(n0 + r) * NM + m;
        float s = 0.f;
#pragma unroll
        for (int cc = 0; cc < 16; ++cc) s += p[(size_t)cc * NN * NM];
        xr[i] = s;
    }
    __syncthreads();

    // layer 1: h1[r][o] = relu(sum_m xr[r][m] * ow1[o][m] + ob1[o]), o = t
    {
        float acc[16];
        const float bias = ob1[t];
#pragma unroll
        for (int r = 0; r < 16; ++r) acc[r] = bias;
        const float* wrow = ow1 + (size_t)t * NM;
#pragma unroll 2
        for (int mq = 0; mq < NM / 4; ++mq) {
            const float4 w = ldg4(wrow + mq * 4);
#pragma unroll
            for (int r = 0; r < 16; ++r) {
                const float4 xv = *reinterpret_cast<const float4*>(&xr[r * NM + mq * 4]);
                acc[r] += xv.x * w.x + xv.y * w.y + xv.z * w.z + xv.w * w.w;
            }
        }
#pragma unroll
        for (int r = 0; r < 16; ++r) h1[r * NOH + t] = fmaxf(acc[r], 0.f);
    }
    __syncthreads();

    // layer 2: h2[r][o] = relu(sum_h h1[r][h] * ow2[o][h] + ob2[o]), o = t
    {
        float acc[16];
        const float bias = ob2[t];
#pragma unroll
        for (int r = 0; r < 16; ++r) acc[r] = bias;
        const float* wrow = ow2 + (size_t)t * NOH;
#pragma unroll 2
        for (int hq = 0; hq < NOH / 4; ++hq) {
            const float4 w = ldg4(wrow + hq * 4);
#pragma unroll
            for (int r = 0; r < 16; ++r) {
                const float4 hv = *reinterpret_cast<const float4*>(&h1[r * NOH + hq * 4]);
                acc[r] += hv.x * w.x + hv.y * w.y + hv.z * w.z + hv.w * w.w;
            }
        }
#pragma unroll
        for (int r = 0; r < 16; ++r) h2[r * NOH + t] = fmaxf(acc[r], 0.f);
    }
    __syncthreads();

    // layer 3 + residual: d = t&63, 4 rows per thread
    {
        const int d  = t & 63;
        const int rg = t >> 6;           // 0..3 -> rows rg*4..+3
        float acc[4] = {0.f, 0.f, 0.f, 0.f};
        const float* wrow = ow3 + (size_t)d * NOH;
#pragma unroll 2
        for (int hq = 0; hq < NOH / 4; ++hq) {
            const float4 w = ldg4(wrow + hq * 4);
#pragma unroll
            for (int r = 0; r < 4; ++r) {
                const float4 hv = *reinterpret_cast<const float4*>(&h2[(rg * 4 + r) * NOH + hq * 4]);
                acc[r] += hv.x * w.x + hv.y * w.y + hv.z * w.z + hv.w * w.w;
            }
        }
        const float bias = ob3[d];
#pragma unroll
        for (int r = 0; r < 4; ++r) {
            const int n = n0 + rg * 4 + r;
            const size_t idx = ((size_t)b * NN + n) * ND + d;
            out[idx] = inputs[idx] + acc[r] + bias;
        }
    }
}

extern "C" void kernel_launch(void* const* d_in, const int* in_sizes, int n_in,
                              void* d_out, int out_size, void* d_ws, size_t ws_size,
                              hipStream_t stream)
{
    const float* inputs   = (const float*)d_in[0];
    const float* rel_rec  = (const float*)d_in[1];
    const float* rel_send = (const float*)d_in[2];
    const float* rel_type = (const float*)d_in[3];
    const int*   indices  = (const int*)  d_in[4];
    const float* w1  = (const float*)d_in[5];
    const float* b1  = (const float*)d_in[6];
    const float* w2  = (const float*)d_in[7];
    const float* b2  = (const float*)d_in[8];
    const float* w3  = (const float*)d_in[9];
    const float* b3  = (const float*)d_in[10];
    const float* w4  = (const float*)d_in[11];
    const float* b4  = (const float*)d_in[12];
    const float* ow1 = (const float*)d_in[13];
    const float* ob1 = (const float*)d_in[14];
    const float* ow2 = (const float*)d_in[15];
    const float* ob2 = (const float*)d_in[16];
    const float* ow3 = (const float*)d_in[17];
    const float* ob3 = (const float*)d_in[18];

    float* partial = (float*)d_ws;           // 512 * 128 * 128 f32 = 32 MB
    float* outf    = (float*)d_out;

    k_edge<<<dim3(512), dim3(256), 0, stream>>>(
        inputs, rel_rec, rel_send, rel_type, indices,
        w1, b1, w2, b2, w3, b3, w4, b4, partial);
    k_out<<<dim3(256), dim3(256), 0, stream>>>(
        partial, inputs, ow1, ob1, ow2, ob2, ow3, ob3, outf);
}

// Round 2
// 298.058 us; speedup vs baseline: 11.7428x; 11.7428x over previous
//
#include <hip/hip_runtime.h>
#include <hip/hip_bf16.h>

#define NB 32
#define NN 128
#define NE 16256
#define ND 64
#define NHID 128
#define NM 128
#define NOH 256
#define NT 2
#define EHALF 8128
#define NTILE 127        // 64-edge tiles per half
#define TILE_E 64

typedef short s16x8 __attribute__((ext_vector_type(8)));
typedef short s16x4 __attribute__((ext_vector_type(4)));
typedef float f32x4 __attribute__((ext_vector_type(4)));

#define MFMA16(a, b, c) __builtin_amdgcn_mfma_f32_16x16x32_bf16((a), (b), (c), 0, 0, 0)

// ---- ws layout (bytes) ----
#define PARTIAL_SZ ((size_t)256 * 128 * 128 * 4)         // 16 MB, [wg][n][m] f32
#define WS_RS      (PARTIAL_SZ)                          // ushort[NE][128]
#define RS_SZ      ((size_t)NE * 128 * 2)
#define WS_RRT     (WS_RS + RS_SZ)                       // ushort[128][NE]
#define RRT_SZ     ((size_t)128 * NE * 2)
#define WS_INPT    (WS_RRT + RRT_SZ)                     // ushort[NB][64][128]
#define INPT_SZ    ((size_t)NB * 64 * 128 * 2)
#define WS_WA      (WS_INPT + INPT_SZ)                   // ushort[2][2][128][64]
#define WA_SZ      ((size_t)2 * 2 * 128 * 64 * 2)
#define WS_WB      (WS_WA + WA_SZ)                       // ushort[2][2][128][128]

__device__ __forceinline__ ushort f2bf(float x) {
    uint u = __float_as_uint(x);
    return (ushort)((u + 0x7fffu + ((u >> 16) & 1u)) >> 16);
}
// XOR-swizzle within a row (G4): byte ^= (row&7)<<4
__device__ __forceinline__ char* swz(void* base, int row, int rowBytes, int bir) {
    return (char*)base + row * rowBytes + (bir ^ ((row & 7) << 4));
}
__device__ __forceinline__ const char* swzc(const void* base, int row, int rowBytes, int bir) {
    return (const char*)base + row * rowBytes + (bir ^ ((row & 7) << 4));
}

// ---------------------------------------------------------------------------
// k_cvt: bf16 conversions + transposes into ws.
// blocks 0..126: rrT; 127..158: inpT; 159..285: rs; 286: weights
// ---------------------------------------------------------------------------
__global__ __launch_bounds__(256)
void k_cvt(const float* __restrict__ inputs, const float* __restrict__ rel_rec,
           const float* __restrict__ rel_send,
           const float* __restrict__ w1, const float* __restrict__ w2,
           const float* __restrict__ w3, const float* __restrict__ w4,
           char* __restrict__ ws)
{
    ushort* rs   = (ushort*)(ws + WS_RS);
    ushort* rrT  = (ushort*)(ws + WS_RRT);
    ushort* inpT = (ushort*)(ws + WS_INPT);
    ushort* wa   = (ushort*)(ws + WS_WA);
    ushort* wb   = (ushort*)(ws + WS_WB);
    const int t = threadIdx.x;
    const int blk = blockIdx.x;
    __shared__ float lds[128][65];

    if (blk < 127) {                       // rrT: transpose rel_rec -> [n][e] bf16
        const int eb = blk;
        for (int nh = 0; nh < 2; ++nh) {
            __syncthreads();
            for (int i = t; i < 128 * 64; i += 256) {
                int e = i >> 6, n = i & 63;
                lds[e][n] = rel_rec[(size_t)(eb * 128 + e) * 128 + nh * 64 + n];
            }
            __syncthreads();
            for (int i = t; i < 64 * 128; i += 256) {
                int n = i >> 7, e = i & 127;
                rrT[(size_t)(nh * 64 + n) * NE + eb * 128 + e] = f2bf(lds[e][n]);
            }
        }
    } else if (blk < 159) {                // inpT: transpose inputs[b] -> [d][n] bf16
        const int b = blk - 127;
        for (int i = t; i < 128 * 64; i += 256) {
            int n = i >> 6, d = i & 63;
            lds[n][d] = inputs[(size_t)b * 8192 + n * 64 + d];
        }
        __syncthreads();
        for (int i = t; i < 64 * 128; i += 256) {
            int d = i >> 7, n = i & 127;
            inpT[(size_t)b * 8192 + d * 128 + n] = f2bf(lds[n][d]);
        }
    } else if (blk < 286) {                // rs: straight convert
        const int eb = blk - 159;
        const float4* src = (const float4*)(rel_send + (size_t)eb * 16384);
        for (int i = t; i < 4096; i += 256) {
            float4 v = src[i];
            ushort4 o;
            o.x = f2bf(v.x); o.y = f2bf(v.y); o.z = f2bf(v.z); o.w = f2bf(v.w);
            *(ushort4*)(rs + (size_t)eb * 16384 + (size_t)i * 4) = o;
        }
    } else {                               // weights
        for (int i = t; i < 32768; i += 256)
            wa[i] = f2bf(i < 16384 ? w1[i] : w3[i - 16384]);
        for (int i = t; i < 65536; i += 256)
            wb[i] = f2bf(i < 32768 ? w2[i] : w4[i - 32768]);
    }
}

// ---------------------------------------------------------------------------
// k_edge: full MFMA chain per 64-edge tile. grid 256 = b*8 + half*4 + chunk.
// ---------------------------------------------------------------------------
__global__ __launch_bounds__(512, 2)
void k_edge(const float* __restrict__ rel_type, const int* __restrict__ indices,
            const float* __restrict__ b1, const float* __restrict__ b2,
            const float* __restrict__ b3, const float* __restrict__ b4,
            char* __restrict__ ws)
{
    const ushort* rs  = (const ushort*)(ws + WS_RS);
    const ushort* rrT = (const ushort*)(ws + WS_RRT);
    float* partial    = (float*)(ws);

    const int tid  = threadIdx.x;
    const int wave = tid >> 6;
    const int lane = tid & 63;
    const int l16  = lane & 15;
    const int l4   = lane >> 4;

    const int wg    = blockIdx.x;
    const int b     = wg >> 3;
    const int half  = (wg >> 2) & 1;
    const int chunk = wg & 3;

    const ushort* inpT = (const ushort*)(ws + WS_INPT) + (size_t)b * 8192;
    const ushort* wa   = (const ushort*)(ws + WS_WA) + (size_t)half * 2 * 128 * 64;
    const ushort* wb   = (const ushort*)(ws + WS_WB) + (size_t)half * 2 * 128 * 128;
    const float*  BA   = half ? b3 : b1;
    const float*  BB   = half ? b4 : b2;

    __shared__ ushort X_s[64 * 64];     //  8 KB, rows 128B (e-major)
    __shared__ ushort H_s[64 * 128];    // 16 KB, rows 256B (e-major)
    __shared__ ushort Mt_s[128 * 64];   // 16 KB, rows 128B (m-major)
    __shared__ ushort rr_s[128 * 64];   // 16 KB, rows 128B (n-major)
    __shared__ int    idx_s[64];
    __shared__ float  rt_s[64 * 2];

    // persistent B-fragments: WA (h-layer), WB (m-layer), inpT (X-layer)
    s16x8 wA[2][2], wB[2][4], wX[2][4];
    float biasA[2], biasB[2];
    for (int it = 0; it < 2; ++it) {
        for (int ks = 0; ks < 2; ++ks)
            wA[it][ks] = *(const s16x8*)(wa + ((size_t)it * 128 + wave * 16 + l16) * 64 + ks * 32 + l4 * 8);
        for (int ks = 0; ks < 4; ++ks)
            wB[it][ks] = *(const s16x8*)(wb + ((size_t)it * 128 + wave * 16 + l16) * 128 + ks * 32 + l4 * 8);
        biasA[it] = BA[it * 128 + wave * 16 + l16];
        biasB[it] = BB[it * 128 + wave * 16 + l16];
    }
    for (int cc = 0; cc < 2; ++cc) {
        const int d = ((wave & 1) * 2 + cc) * 16 + l16;
        for (int ks = 0; ks < 4; ++ks)
            wX[cc][ks] = *(const s16x8*)(inpT + (size_t)d * 128 + ks * 32 + l4 * 8);
    }

    f32x4 agg[8];
    for (int r = 0; r < 8; ++r) agg[r] = (f32x4){0.f, 0.f, 0.f, 0.f};

    const int t0 = chunk * 32;
    const int t1 = (t0 + 32 < NTILE) ? (t0 + 32) : NTILE;

    for (int tile = t0; tile < t1; ++tile) {
        const int e_base = tile * TILE_E;
        __syncthreads();                                    // (A) prev tile done
        if (tid < 64) {
            idx_s[tid] = indices[half * EHALF + e_base + tid];
        } else if (tid < 192) {
            int q = tid - 64, e = q >> 1, it = q & 1;
            int eg = indices[half * EHALF + e_base + e];
            rt_s[q] = rel_type[((size_t)b * NE + eg) * NT + it];
        }
        __syncthreads();                                    // (B)

        // stage rrT tile -> rr_s (swizzled)
        const int eg0 = idx_s[0];
        for (int i = tid; i < 1024; i += 512) {
            int n = i >> 3, c = i & 7;
            s16x8 v = *(const s16x8*)(rrT + (size_t)n * NE + eg0 + c * 8);
            *(s16x8*)swz(rr_s, n, 128, c * 16) = v;
        }

        // ---- X = RS @ inpT  (K=128) ----
        {
            const int rt = wave >> 1;
            const int erow = rt * 16 + l16;
            const ushort* arow = rs + (size_t)idx_s[erow] * 128 + l4 * 8;
            s16x8 a0 = *(const s16x8*)(arow);
            s16x8 a1 = *(const s16x8*)(arow + 32);
            s16x8 a2 = *(const s16x8*)(arow + 64);
            s16x8 a3 = *(const s16x8*)(arow + 96);
            for (int cc = 0; cc < 2; ++cc) {
                const int ct = (wave & 1) * 2 + cc;
                const int d  = ct * 16 + l16;
                f32x4 c = (f32x4){0.f, 0.f, 0.f, 0.f};
                c = MFMA16(a0, wX[cc][0], c);
                c = MFMA16(a1, wX[cc][1], c);
                c = MFMA16(a2, wX[cc][2], c);
                c = MFMA16(a3, wX[cc][3], c);
                for (int r = 0; r < 4; ++r) {
                    int e = rt * 16 + l4 * 4 + r;
                    *(ushort*)swz(X_s, e, 128, d * 2) = f2bf(c[r]);
                }
            }
        }
        __syncthreads();                                    // (C)

        float msg_acc[4][4];
        for (int rt = 0; rt < 4; ++rt)
            for (int r = 0; r < 4; ++r) msg_acc[rt][r] = 0.f;

        for (int it = 0; it < 2; ++it) {
            // ---- H = relu(X @ WA^T + bA)  (K=64), wave owns h-cols wave*16.. ----
            for (int rt = 0; rt < 4; ++rt) {
                int e = rt * 16 + l16;
                s16x8 a0 = *(const s16x8*)swzc(X_s, e, 128, (l4 * 8) * 2);
                s16x8 a1 = *(const s16x8*)swzc(X_s, e, 128, (32 + l4 * 8) * 2);
                f32x4 c = (f32x4){0.f, 0.f, 0.f, 0.f};
                c = MFMA16(a0, wA[it][0], c);
                c = MFMA16(a1, wA[it][1], c);
                for (int r = 0; r < 4; ++r) {
                    int er = rt * 16 + l4 * 4 + r;
                    *(ushort*)swz(H_s, er, 256, (wave * 16 + l16) * 2) =
                        f2bf(fmaxf(c[r] + biasA[it], 0.f));
                }
            }
            __syncthreads();                                // (D)
            // ---- M += relu(H @ WB^T + bB) * rt  (K=128) ----
            for (int rt = 0; rt < 4; ++rt) {
                int e = rt * 16 + l16;
                f32x4 c = (f32x4){0.f, 0.f, 0.f, 0.f};
                for (int ks = 0; ks < 4; ++ks) {
                    s16x8 a = *(const s16x8*)swzc(H_s, e, 256, (ks * 32 + l4 * 8) * 2);
                    c = MFMA16(a, wB[it][ks], c);
                }
                for (int r = 0; r < 4; ++r) {
                    int er = rt * 16 + l4 * 4 + r;
                    msg_acc[rt][r] += fmaxf(c[r] + biasB[it], 0.f) * rt_s[er * 2 + it];
                }
            }
            if (it == 0) __syncthreads();                   // (E) before H rewrite
        }

        // ---- write msgT (m-major, packed b64) ----
        {
            const int m = wave * 16 + l16;
            for (int rt = 0; rt < 4; ++rt) {
                int e0 = rt * 16 + l4 * 4;
                s16x4 v;
                v[0] = (short)f2bf(msg_acc[rt][0]);
                v[1] = (short)f2bf(msg_acc[rt][1]);
                v[2] = (short)f2bf(msg_acc[rt][2]);
                v[3] = (short)f2bf(msg_acc[rt][3]);
                *(s16x4*)swz(Mt_s, m, 128, e0 * 2) = v;
            }
        }
        __syncthreads();                                    // (H)

        // ---- agg += rrT @ msg  (K=64) ----
        {
            const int m = wave * 16 + l16;
            s16x8 bB0 = *(const s16x8*)swzc(Mt_s, m, 128, (l4 * 8) * 2);
            s16x8 bB1 = *(const s16x8*)swzc(Mt_s, m, 128, (32 + l4 * 8) * 2);
            for (int rt = 0; rt < 8; ++rt) {
                int n = rt * 16 + l16;
                s16x8 a0 = *(const s16x8*)swzc(rr_s, n, 128, (l4 * 8) * 2);
                s16x8 a1 = *(const s16x8*)swzc(rr_s, n, 128, (32 + l4 * 8) * 2);
                agg[rt] = MFMA16(a0, bB0, agg[rt]);
                agg[rt] = MFMA16(a1, bB1, agg[rt]);
            }
        }
    }

    // write 128x128 f32 partial
    float* dst = partial + (size_t)wg * (128 * 128);
    const int m = wave * 16 + l16;
    for (int rt = 0; rt < 8; ++rt)
        for (int r = 0; r < 4; ++r)
            dst[(size_t)(rt * 16 + l4 * 4 + r) * 128 + m] = agg[rt][r];
}

// ---------------------------------------------------------------------------
// k_out: reduce 8 partials -> node MLP 128->256->256->64 + residual (f32)
// ---------------------------------------------------------------------------
__device__ __forceinline__ float4 ldg4(const float* p) {
    return *reinterpret_cast<const float4*>(p);
}

__global__ __launch_bounds__(256)
void k_out(const float* __restrict__ partial,
           const float* __restrict__ inputs,
           const float* __restrict__ ow1, const float* __restrict__ ob1,
           const float* __restrict__ ow2, const float* __restrict__ ob2,
           const float* __restrict__ ow3, const float* __restrict__ ob3,
           float* __restrict__ out)
{
    const int t  = threadIdx.x;
    const int wg = blockIdx.x;      // 0..255
    const int b  = wg >> 3;
    const int n0 = (wg & 7) * 16;

    __shared__ float xr[16 * NM];
    __shared__ float h1[16 * NOH];
    __shared__ float h2[16 * NOH];

    for (int i = t; i < 16 * NM; i += 256) {
        const int r = i >> 7, m = i & 127;
        const float* p = partial + (size_t)(b * 8) * (NN * NM) + (size_t)(n0 + r) * NM + m;
        float s = 0.f;
#pragma unroll
        for (int cc = 0; cc < 8; ++cc) s += p[(size_t)cc * NN * NM];
        xr[i] = s;
    }
    __syncthreads();

    {
        float acc[16];
        const float bias = ob1[t];
#pragma unroll
        for (int r = 0; r < 16; ++r) acc[r] = bias;
        const float* wrow = ow1 + (size_t)t * NM;
#pragma unroll 2
        for (int mq = 0; mq < NM / 4; ++mq) {
            const float4 w = ldg4(wrow + mq * 4);
#pragma unroll
            for (int r = 0; r < 16; ++r) {
                const float4 xv = *reinterpret_cast<const float4*>(&xr[r * NM + mq * 4]);
                acc[r] += xv.x * w.x + xv.y * w.y + xv.z * w.z + xv.w * w.w;
            }
        }
#pragma unroll
        for (int r = 0; r < 16; ++r) h1[r * NOH + t] = fmaxf(acc[r], 0.f);
    }
    __syncthreads();

    {
        float acc[16];
        const float bias = ob2[t];
#pragma unroll
        for (int r = 0; r < 16; ++r) acc[r] = bias;
        const float* wrow = ow2 + (size_t)t * NOH;
#pragma unroll 2
        for (int hq = 0; hq < NOH / 4; ++hq) {
            const float4 w = ldg4(wrow + hq * 4);
#pragma unroll
            for (int r = 0; r < 16; ++r) {
                const float4 hv = *reinterpret_cast<const float4*>(&h1[r * NOH + hq * 4]);
                acc[r] += hv.x * w.x + hv.y * w.y + hv.z * w.z + hv.w * w.w;
            }
        }
#pragma unroll
        for (int r = 0; r < 16; ++r) h2[r * NOH + t] = fmaxf(acc[r], 0.f);
    }
    __syncthreads();

    {
        const int d  = t & 63;
        const int rg = t >> 6;
        float acc[4] = {0.f, 0.f, 0.f, 0.f};
        const float* wrow = ow3 + (size_t)d * NOH;
#pragma unroll 2
        for (int hq = 0; hq < NOH / 4; ++hq) {
            const float4 w = ldg4(wrow + hq * 4);
#pragma unroll
            for (int r = 0; r < 4; ++r) {
                const float4 hv = *reinterpret_cast<const float4*>(&h2[(rg * 4 + r) * NOH + hq * 4]);
                acc[r] += hv.x * w.x + hv.y * w.y + hv.z * w.z + hv.w * w.w;
            }
        }
        const float bias = ob3[d];
#pragma unroll
        for (int r = 0; r < 4; ++r) {
            const int n = n0 + rg * 4 + r;
            const size_t idx = ((size_t)b * NN + n) * ND + d;
            out[idx] = inputs[idx] + acc[r] + bias;
        }
    }
}

extern "C" void kernel_launch(void* const* d_in, const int* in_sizes, int n_in,
                              void* d_out, int out_size, void* d_ws, size_t ws_size,
                              hipStream_t stream)
{
    const float* inputs   = (const float*)d_in[0];
    const float* rel_rec  = (const float*)d_in[1];
    const float* rel_send = (const float*)d_in[2];
    const float* rel_type = (const float*)d_in[3];
    const int*   indices  = (const int*)  d_in[4];
    const float* w1  = (const float*)d_in[5];
    const float* b1  = (const float*)d_in[6];
    const float* w2  = (const float*)d_in[7];
    const float* b2  = (const float*)d_in[8];
    const float* w3  = (const float*)d_in[9];
    const float* b3  = (const float*)d_in[10];
    const float* w4  = (const float*)d_in[11];
    const float* b4  = (const float*)d_in[12];
    const float* ow1 = (const float*)d_in[13];
    const float* ob1 = (const float*)d_in[14];
    const float* ow2 = (const float*)d_in[15];
    const float* ob2 = (const float*)d_in[16];
    const float* ow3 = (const float*)d_in[17];
    const float* ob3 = (const float*)d_in[18];

    char* ws = (char*)d_ws;

    k_cvt<<<dim3(287), dim3(256), 0, stream>>>(inputs, rel_rec, rel_send,
                                               w1, w2, w3, w4, ws);
    k_edge<<<dim3(256), dim3(512), 0, stream>>>(rel_type, indices,
                                                b1, b2, b3, b4, ws);
    k_out<<<dim3(256), dim3(256), 0, stream>>>((const float*)ws, inputs,
                                               ow1, ob1, ow2, ob2, ow3, ob3,
                                               (float*)d_out);
}